// Round 1
// baseline (411.157 us; speedup 1.0000x reference)
//
#include <hip/hip_runtime.h>
#include <hip/hip_bf16.h>
#include <cstdint>

#define NN 50000
#define NE 800000
#define DH 128
#define TILES 50000   // NE/16

typedef __bf16 bf16;
typedef __bf16 bf16x8 __attribute__((ext_vector_type(8)));
typedef float  f32x4  __attribute__((ext_vector_type(4)));

__device__ __forceinline__ float fast_silu(float x) {
    float e = __expf(-x);
    return x * __builtin_amdgcn_rcpf(1.0f + e);
}

// ---------------- k0: weight prep (transpose + bf16) ----------------
__global__ void prep_kernel(const float* __restrict__ W1, const float* __restrict__ W2,
                            const float* __restrict__ W3, const float* __restrict__ b1,
                            const float* __restrict__ g1, const float* __restrict__ bt1,
                            const float* __restrict__ b2, const float* __restrict__ b3,
                            const float* __restrict__ W4,
                            bf16* __restrict__ w1aT, bf16* __restrict__ w1bT,
                            bf16* __restrict__ w2T,  bf16* __restrict__ w3T,
                            float* __restrict__ smalls) {
    int i = blockIdx.x * 256 + threadIdx.x;   // 0..16383
    int n = i >> 7, k = i & 127;
    w1aT[i] = (bf16)W1[k * DH + n];
    w1bT[i] = (bf16)W1[(k + DH) * DH + n];
    w2T[i]  = (bf16)W2[k * DH + n];
    w3T[i]  = (bf16)W3[k * DH + n];
    if (i < DH) {
        smalls[i]          = W1[256 * DH + i]; // w1c
        smalls[DH + i]     = b1[i];
        smalls[2 * DH + i] = g1[i];
        smalls[3 * DH + i] = bt1[i];
        smalls[4 * DH + i] = b2[i];
        smalls[5 * DH + i] = b3[i];
        smalls[6 * DH + i] = W4[i];
    }
}

// ---------------- k1: A = h@W1a, B = h@W1b (bf16 out) ----------------
__global__ __launch_bounds__(256) void node_kernel(const float* __restrict__ h,
                                                   const bf16* __restrict__ w1aT,
                                                   const bf16* __restrict__ w1bT,
                                                   bf16* __restrict__ An,
                                                   bf16* __restrict__ Bn) {
    int lane = threadIdx.x & 63, wid = threadIdx.x >> 6;
    int r = lane & 15, g = lane >> 4;
    int wt = blockIdx.x * 4 + wid;
    if (wt >= (NN / 16)) return;
    int base = wt * 16;
    int node = base + r;

    bf16x8 ha[4];
#pragma unroll
    for (int s = 0; s < 4; s++) {
        const float* hp = h + (size_t)node * DH + s * 32 + g * 8;
        float4 p0 = *(const float4*)hp;
        float4 p1 = *(const float4*)(hp + 4);
        ha[s][0] = (bf16)p0.x; ha[s][1] = (bf16)p0.y;
        ha[s][2] = (bf16)p0.z; ha[s][3] = (bf16)p0.w;
        ha[s][4] = (bf16)p1.x; ha[s][5] = (bf16)p1.y;
        ha[s][6] = (bf16)p1.z; ha[s][7] = (bf16)p1.w;
    }
#pragma unroll
    for (int t = 0; t < 16; t++) {
        const bf16* wmat = (t < 8) ? w1aT : w1bT;
        int n = (t & 7) * 16 + r;
        f32x4 acc = {0.f, 0.f, 0.f, 0.f};
#pragma unroll
        for (int s = 0; s < 4; s++) {
            bf16x8 wb = *(const bf16x8*)(wmat + n * DH + s * 32 + g * 8);
            acc = __builtin_amdgcn_mfma_f32_16x16x32_bf16(ha[s], wb, acc, 0, 0, 0);
        }
        bf16* dst = (t < 8) ? An : Bn;
#pragma unroll
        for (int jj = 0; jj < 4; jj++)
            dst[(size_t)(base + g * 4 + jj) * DH + (t & 7) * 16 + r] = (bf16)acc[jj];
    }
}

// ---------------- k2: out = x ----------------
__global__ void init_kernel(const float* __restrict__ x, float* __restrict__ out, int n) {
    int i = blockIdx.x * 256 + threadIdx.x;
    if (i < n) out[i] = x[i];
}

// ---------------- k3: fused edge MLP + scatter ----------------
__global__ __launch_bounds__(512, 2) void edge_kernel(
    const bf16* __restrict__ An, const bf16* __restrict__ Bn,
    const bf16* __restrict__ w2T, const bf16* __restrict__ w3T,
    const float* __restrict__ smalls, const float* __restrict__ b4p,
    const int* __restrict__ e, const float* __restrict__ dxv,
    const float* __restrict__ d2, float* __restrict__ out) {
    __shared__ __align__(16) bf16 sW2[128 * 136];
    __shared__ __align__(16) bf16 sW3[128 * 136];
    __shared__ __align__(16) bf16 sY[8 * 16 * 136];
    __shared__ float sSm[7 * 128];

    int tid = threadIdx.x;
    for (int c = tid; c < 2048; c += 512) {        // 2048 chunks of 8 bf16
        int row = c >> 4, col = (c & 15) * 8;
        *(bf16x8*)&sW2[row * 136 + col] = *(const bf16x8*)&w2T[row * 128 + col];
        *(bf16x8*)&sW3[row * 136 + col] = *(const bf16x8*)&w3T[row * 128 + col];
    }
    if (tid < 128) {
#pragma unroll
        for (int a = 0; a < 7; a++) sSm[a * 128 + tid] = smalls[a * 128 + tid];
    }
    __syncthreads();

    const float* s_w1c = sSm;
    const float* s_b1  = sSm + 128;
    const float* s_g1  = sSm + 256;
    const float* s_bt1 = sSm + 384;
    const float* s_b2  = sSm + 512;
    const float* s_b3  = sSm + 640;
    const float* s_W4  = sSm + 768;
    float b4v = b4p[0];

    int lane = tid & 63, wid = tid >> 6;
    int r = lane & 15, g = lane >> 4;
    bf16* yw = &sY[wid * 16 * 136];
    int wgid = blockIdx.x * 8 + wid;
    int nw = gridDim.x * 8;

    for (int tile = wgid; tile < TILES; tile += nw) {
        int base = tile * 16;
        int ei = e[base + r];
        int ej = e[NE + base + r];
        float d2v = d2[base + r];
        const bf16* Ar = An + (size_t)ei * DH;
        const bf16* Br = Bn + (size_t)ej * DH;

        // z = silu(A[ei] + B[ej] + d2*w1c + b1), in A-frag layout
        float z[4][8];
#pragma unroll
        for (int s = 0; s < 4; s++) {
            bf16x8 av = *(const bf16x8*)(Ar + s * 32 + g * 8);
            bf16x8 bv = *(const bf16x8*)(Br + s * 32 + g * 8);
#pragma unroll
            for (int j = 0; j < 8; j++) {
                int f = s * 32 + g * 8 + j;
                float zz = (float)av[j] + (float)bv[j] + d2v * s_w1c[f] + s_b1[f];
                z[s][j] = fast_silu(zz);
            }
        }
        // LayerNorm across 128 features (4 lanes per row: xor 16, 32)
        float sum = 0.f, sq = 0.f;
#pragma unroll
        for (int s = 0; s < 4; s++)
#pragma unroll
            for (int j = 0; j < 8; j++) { sum += z[s][j]; sq += z[s][j] * z[s][j]; }
        sum += __shfl_xor(sum, 16); sq += __shfl_xor(sq, 16);
        sum += __shfl_xor(sum, 32); sq += __shfl_xor(sq, 32);
        float mu = sum * 0.0078125f;
        float var = sq * 0.0078125f - mu * mu;
        float rs = __builtin_amdgcn_rsqf(var + 1e-5f);

        bf16x8 af[4];
#pragma unroll
        for (int s = 0; s < 4; s++)
#pragma unroll
            for (int j = 0; j < 8; j++) {
                int f = s * 32 + g * 8 + j;
                af[s][j] = (bf16)((z[s][j] - mu) * rs * s_g1[f] + s_bt1[f]);
            }

        // GEMM1: y = silu(zn @ W2 + b2) -> per-wave LDS tile (layout exchange)
#pragma unroll
        for (int t = 0; t < 8; t++) {
            f32x4 acc = {0.f, 0.f, 0.f, 0.f};
#pragma unroll
            for (int s = 0; s < 4; s++) {
                bf16x8 wb = *(const bf16x8*)&sW2[(t * 16 + r) * 136 + s * 32 + g * 8];
                acc = __builtin_amdgcn_mfma_f32_16x16x32_bf16(af[s], wb, acc, 0, 0, 0);
            }
            int n = t * 16 + r;
            float b2n = s_b2[n];
#pragma unroll
            for (int jj = 0; jj < 4; jj++)
                yw[(g * 4 + jj) * 136 + n] = (bf16)fast_silu(acc[jj] + b2n);
        }
        // reload y as A-fragments
        bf16x8 a2[4];
#pragma unroll
        for (int s = 0; s < 4; s++)
            a2[s] = *(const bf16x8*)&yw[r * 136 + s * 32 + g * 8];

        // GEMM2 + fused silu*W4 reduction
        float part[4] = {0.f, 0.f, 0.f, 0.f};
#pragma unroll
        for (int t = 0; t < 8; t++) {
            f32x4 acc = {0.f, 0.f, 0.f, 0.f};
#pragma unroll
            for (int s = 0; s < 4; s++) {
                bf16x8 wb = *(const bf16x8*)&sW3[(t * 16 + r) * 136 + s * 32 + g * 8];
                acc = __builtin_amdgcn_mfma_f32_16x16x32_bf16(a2[s], wb, acc, 0, 0, 0);
            }
            int n = t * 16 + r;
            float b3n = s_b3[n], w4n = s_W4[n];
#pragma unroll
            for (int jj = 0; jj < 4; jj++)
                part[jj] += fast_silu(acc[jj] + b3n) * w4n;
        }
#pragma unroll
        for (int jj = 0; jj < 4; jj++) {
            part[jj] += __shfl_xor(part[jj], 1);
            part[jj] += __shfl_xor(part[jj], 2);
            part[jj] += __shfl_xor(part[jj], 4);
            part[jj] += __shfl_xor(part[jj], 8);
        }
        // scatter: edge m = g*4+jj, component r (<3)
#pragma unroll
        for (int jj = 0; jj < 4; jj++) {
            float scale = part[jj] + b4v;
            int m = g * 4 + jj;
            int eim = __shfl(ei, m);
            if (r < 3)
                atomicAdd(&out[(size_t)eim * 3 + r],
                          dxv[(size_t)(base + m) * 3 + r] * scale);
        }
    }
}

extern "C" void kernel_launch(void* const* d_in, const int* in_sizes, int n_in,
                              void* d_out, int out_size, void* d_ws, size_t ws_size,
                              hipStream_t stream) {
    const float* h   = (const float*)d_in[0];
    const float* x   = (const float*)d_in[1];
    const int*   e   = (const int*)d_in[2];
    const float* dxv = (const float*)d_in[3];
    const float* d2  = (const float*)d_in[4];
    const float* W1  = (const float*)d_in[5];
    const float* b1  = (const float*)d_in[6];
    const float* g1  = (const float*)d_in[7];
    const float* bt1 = (const float*)d_in[8];
    const float* W2  = (const float*)d_in[9];
    const float* b2  = (const float*)d_in[10];
    const float* W3  = (const float*)d_in[11];
    const float* b3  = (const float*)d_in[12];
    const float* W4  = (const float*)d_in[13];
    const float* b4  = (const float*)d_in[14];

    char* ws = (char*)d_ws;
    bf16* An    = (bf16*)(ws);
    bf16* Bn    = (bf16*)(ws + 12800000);
    bf16* w1aT  = (bf16*)(ws + 25600000);
    bf16* w1bT  = (bf16*)(ws + 25600000 + 32768);
    bf16* w2T   = (bf16*)(ws + 25600000 + 65536);
    bf16* w3T   = (bf16*)(ws + 25600000 + 98304);
    float* smalls = (float*)(ws + 25600000 + 131072);
    float* out  = (float*)d_out;

    prep_kernel<<<64, 256, 0, stream>>>(W1, W2, W3, b1, g1, bt1, b2, b3, W4,
                                        w1aT, w1bT, w2T, w3T, smalls);
    node_kernel<<<(NN / 16 + 3) / 4, 256, 0, stream>>>(h, w1aT, w1bT, An, Bn);
    init_kernel<<<(NN * 3 + 255) / 256, 256, 0, stream>>>(x, out, NN * 3);
    edge_kernel<<<256, 512, 0, stream>>>(An, Bn, w2T, w3T, smalls, b4,
                                         e, dxv, d2, out);
}